// Round 8
// baseline (226.292 us; speedup 1.0000x reference)
//
#include <hip/hip_runtime.h>
#include <hip/hip_bf16.h>

typedef __bf16 bf16;
typedef __bf16 bf16x8 __attribute__((ext_vector_type(8)));
typedef __bf16 bf16x4 __attribute__((ext_vector_type(4)));
typedef __bf16 bf16x2 __attribute__((ext_vector_type(2)));
typedef float floatx4 __attribute__((ext_vector_type(4)));
typedef float floatx16 __attribute__((ext_vector_type(16)));
typedef int intx4 __attribute__((ext_vector_type(4)));

#define B_SZ 2
#define S_LEN 2048
#define D_DIM 1024
#define H_CNT 16
#define HD_DIM 64
#define M_ROWS 4096   // B*S
#define QSCALE 0.18033688011112042f  // 0.125 * log2(e): scores come out in base-2 domain

__device__ __forceinline__ void async_ld16(const void* g, void* s) {
    __builtin_amdgcn_global_load_lds((const __attribute__((address_space(1))) void*)g,
                                     (__attribute__((address_space(3))) void*)s, 16, 0, 0);
}

__device__ __forceinline__ floatx4 mfma16(bf16x8 a, bf16x8 b, floatx4 c) {
    return __builtin_amdgcn_mfma_f32_16x16x32_bf16(a, b, c, 0, 0, 0);
}
__device__ __forceinline__ floatx16 mfma32(bf16x8 a, bf16x8 b, floatx16 c) {
    return __builtin_amdgcn_mfma_f32_32x32x16_bf16(a, b, c, 0, 0, 0);
}

// T12 fragment assembly: one permlane32_swap fills two output words (validated R1/R4).
__device__ __forceinline__ bf16x8 mkfrag(int a0, int a1, int b0, int b1) {
    asm("v_permlane32_swap_b32 %0, %1" : "+v"(a0), "+v"(b0));
    asm("v_permlane32_swap_b32 %0, %1" : "+v"(a1), "+v"(b1));
    intx4 q = {a0, a1, b0, b1};
    return __builtin_bit_cast(bf16x8, q);
}

// ---------------- prep: weight transposes only (input casts folded into qkv GEMM) ----------------
struct PrepArgs {
    const float* w_src[3];    bf16* w_dst[3];
    const float* wo;          bf16* wo_t;
};
__global__ __launch_bounds__(256) void prep(PrepArgs a) {
    __shared__ bf16 tile[32][33];
    const int bx = blockIdx.x, tid = threadIdx.x;
    int tx = tid & 31, ty = tid >> 5;
    const float* src; bf16* dst; int r0, c0, C, R;
    if (bx < 3072) {
        int z = bx >> 6, xy = bx & 63;
        int mat = z >> 4, head = z & 15;
        src = a.w_src[mat] + (size_t)head * D_DIM * HD_DIM;  // [1024][64]
        dst = a.w_dst[mat] + (size_t)head * D_DIM * HD_DIM;  // [64][1024]
        r0 = (xy & 31) * 32; c0 = (xy >> 5) * 32; C = HD_DIM; R = D_DIM;
    } else {
        int idx = bx - 3072;
        src = a.wo; dst = a.wo_t;
        r0 = (idx & 31) * 32; c0 = (idx >> 5) * 32; C = D_DIM; R = D_DIM;
    }
#pragma unroll
    for (int i = 0; i < 32; i += 8)
        tile[ty + i][tx] = (bf16)src[(size_t)(r0 + ty + i) * C + c0 + tx];
    __syncthreads();
#pragma unroll
    for (int i = 0; i < 32; i += 8)
        dst[(size_t)(c0 + ty + i) * R + r0 + tx] = tile[tx][ty + i];
}

// ---------------- QKV GEMM: C = (f32 A[4096x1024] * BT^T + bias) * scale ----------------
// A is staged as RAW F32 via global_load_lds (async semantics preserved -- the R5 failure
// was reg-staging's load->wait->ds_write serialization; this keeps loads in flight until
// the same barrier as before). f32->bf16 cast happens at the LDS->register fragment read
// (compiler packs to v_cvt_pk_bf16_f32, m240). Identical RNE numerics to the old prep cast.
// A-tile LDS layout: [row][32 f32], chunk position p holds global k-chunk p ^ (row&7)
// (involution; linear gload_lds dest + permuted per-lane SOURCE address, rule-21 style).
// Read of fragment quad q at row r: float4 pair at positions (2q)^(r&7), (2q+1)^(r&7);
// lanes 0..15 -> addr 36*r mod 32 banks -> 2-way aliasing = free.
// mode: 1 = bf16 [b,h,s,hd]; 2 = bf16 V^T [b,h,hd,s]
struct GemmPtrs { const float* Af; const bf16* BT; const float* bias; bf16* C;
                  float scale; int mode; };
struct GemmArgs { GemmPtrs p[3]; };

__global__ __launch_bounds__(256) void gemm_bt(GemmArgs args) {
    __shared__ __align__(16) float As[128 * 32];   // 16 KB f32 A tile
    __shared__ __align__(16) bf16 Bs[128 * 32];    // 8 KB bf16 B tile
    const GemmPtrs P = args.p[blockIdx.z];
    const int tid = threadIdx.x, wave = tid >> 6, lane = tid & 63;
    const int quad = lane >> 4, l15 = lane & 15;
    const int bm = blockIdx.x * 128, bn = blockIdx.y * 128;
    const int wm = (wave >> 1) * 64, wn = (wave & 1) * 64;

    floatx4 acc[4][4];
#pragma unroll
    for (int i = 0; i < 4; i++)
#pragma unroll
        for (int j = 0; j < 4; j++) acc[i][j] = (floatx4){0.f, 0.f, 0.f, 0.f};

    // B staging/read swizzle (unchanged, validated)
    const int srow = (lane >> 2);
    const int scol = (((lane & 3) ^ ((srow >> 1) & 3)) << 3);
    const int ck = ((quad ^ ((l15 >> 1) & 3)) << 3);
    // A staging geometry: issue i covers LDS f32 [i*256 .. i*256+1023], lane's 16B at
    // flat = i*256 + lane*4 -> row = i*8 + (lane>>3), pos = lane&7, src chunk = pos^(row&7)
    const int arl = lane >> 3, apos = lane & 7;

    for (int k0 = 0; k0 < 1024; k0 += 32) {
#pragma unroll
        for (int it = 0; it < 4; ++it) {          // A: 16 issues of 1KB (f32)
            int i = it * 4 + wave;
            int row = i * 8 + arl;
            int c = apos ^ (row & 7);
            async_ld16(P.Af + (size_t)(bm + row) * 1024 + k0 + c * 4, &As[i * 256]);
        }
#pragma unroll
        for (int it = 0; it < 2; ++it) {          // B: 8 issues of 1KB (bf16)
            int issue = it * 4 + wave;
            int row = issue * 16 + srow;
            async_ld16(P.BT + (size_t)(bn + row) * 1024 + k0 + scol, &Bs[issue * 512]);
        }
        __syncthreads();
        bf16x8 af[4], bfr[4];
#pragma unroll
        for (int mi = 0; mi < 4; mi++) {
            int r = wm + mi * 16 + l15;
            int p0 = (2 * quad) ^ (r & 7), p1 = (2 * quad + 1) ^ (r & 7);
            float4 f0 = *(const float4*)&As[r * 32 + p0 * 4];
            float4 f1 = *(const float4*)&As[r * 32 + p1 * 4];
            af[mi] = (bf16x8){(bf16)f0.x, (bf16)f0.y, (bf16)f0.z, (bf16)f0.w,
                              (bf16)f1.x, (bf16)f1.y, (bf16)f1.z, (bf16)f1.w};
        }
#pragma unroll
        for (int ni = 0; ni < 4; ni++)
            bfr[ni] = *(const bf16x8*)&Bs[(wn + ni * 16 + l15) * 32 + ck];
#pragma unroll
        for (int mi = 0; mi < 4; mi++)
#pragma unroll
            for (int ni = 0; ni < 4; ni++) acc[mi][ni] = mfma16(af[mi], bfr[ni], acc[mi][ni]);
        __syncthreads();
    }
#pragma unroll
    for (int ni = 0; ni < 4; ni++) {
        int col = bn + wn + ni * 16 + l15;
        float bb = P.bias[col];
#pragma unroll
        for (int mi = 0; mi < 4; mi++) {
#pragma unroll
            for (int r = 0; r < 4; r++) {
                int row = bm + wm + mi * 16 + quad * 4 + r;
                float v = (acc[mi][ni][r] + bb) * P.scale;
                int b = row >> 11, s2 = row & 2047, h = col >> 6, hd = col & 63;
                if (P.mode == 1)
                    P.C[(((size_t)(b * H_CNT + h)) * S_LEN + s2) * HD_DIM + hd] = (bf16)v;
                else  // mode 2: V^T [b,h,hd,s]
                    P.C[(((size_t)(b * H_CNT + h)) * HD_DIM + hd) * S_LEN + s2] = (bf16)v;
            }
        }
    }
}

// ---------------- output GEMM: 64x64 tiles, bf16 A (ctx), 4 blocks/CU ----------------
__global__ __launch_bounds__(256) void gemm_out64(const bf16* __restrict__ A,
                                                  const bf16* __restrict__ BT,
                                                  const float* __restrict__ bias,
                                                  float* __restrict__ Cf) {
    __shared__ __align__(16) bf16 As[64 * 32];
    __shared__ __align__(16) bf16 Bs[64 * 32];
    const int tid = threadIdx.x, wave = tid >> 6, lane = tid & 63;
    const int quad = lane >> 4, l15 = lane & 15;
    const int bm = blockIdx.x * 64, bn = blockIdx.y * 64;
    const int wm = (wave >> 1) * 32, wn = (wave & 1) * 32;

    floatx4 acc[2][2];
#pragma unroll
    for (int i = 0; i < 2; i++)
#pragma unroll
        for (int j = 0; j < 2; j++) acc[i][j] = (floatx4){0.f, 0.f, 0.f, 0.f};

    const int srow = (lane >> 2);
    const int scol = (((lane & 3) ^ ((srow >> 1) & 3)) << 3);
    const int ck = ((quad ^ ((l15 >> 1) & 3)) << 3);
    for (int k0 = 0; k0 < 1024; k0 += 32) {
        {
            int row = wave * 16 + srow;
            async_ld16(A  + (size_t)(bm + row) * 1024 + k0 + scol, &As[wave * 512]);
            async_ld16(BT + (size_t)(bn + row) * 1024 + k0 + scol, &Bs[wave * 512]);
        }
        __syncthreads();
        bf16x8 af[2], bfr[2];
#pragma unroll
        for (int mi = 0; mi < 2; mi++)
            af[mi] = *(const bf16x8*)&As[(wm + mi * 16 + l15) * 32 + ck];
#pragma unroll
        for (int ni = 0; ni < 2; ni++)
            bfr[ni] = *(const bf16x8*)&Bs[(wn + ni * 16 + l15) * 32 + ck];
#pragma unroll
        for (int mi = 0; mi < 2; mi++)
#pragma unroll
            for (int ni = 0; ni < 2; ni++) acc[mi][ni] = mfma16(af[mi], bfr[ni], acc[mi][ni]);
        __syncthreads();
    }
#pragma unroll
    for (int ni = 0; ni < 2; ni++) {
        int col = bn + wn + ni * 16 + l15;
        float bb = bias[col];
#pragma unroll
        for (int mi = 0; mi < 2; mi++) {
#pragma unroll
            for (int r = 0; r < 4; r++) {
                int row = bm + wm + mi * 16 + quad * 4 + r;
                Cf[(size_t)row * 1024 + col] = acc[mi][ni][r] + bb;
            }
        }
    }
}

// ---------------- flash attention: t-split 2-way inside a 512-thread block ----------------
// R4 body verbatim (best measured: 47.6-48.6us, occupancy 33%, VGPR 56, MfmaUtil ~28%).
// R6 taught: 8 waves/SIMD impossible (VGPR<=64 forces accumulator spill, 1.2GB scratch).
__global__ __launch_bounds__(512, 4) void attn(const bf16* __restrict__ Qg, const bf16* __restrict__ Kg,
                                               const bf16* __restrict__ Vtg, bf16* __restrict__ ctx) {
    __shared__ __align__(16) bf16 smem[32768];    // 64 KB
    const int tid = threadIdx.x, wave = tid >> 6, lane = tid & 63;
    const int l31 = lane & 31, half = lane >> 5;
    const int grp = wave >> 2, wg = wave & 3;     // t-group, wave-in-group
    const int bid = blockIdx.x;
    const int bh = (bid >> 1) & 31;               // L2 swizzle bijection
    const int qb = ((bid >> 6) << 1) | (bid & 1);
    const int q0blk = qb * 128;
    const bf16* Kp = Kg + (size_t)bh * S_LEN * HD_DIM;
    const bf16* Vp = Vtg + (size_t)bh * HD_DIM * S_LEN;
    const int tbase = grp * 1024;

    const int f0 = wg * 512 + lane * 8, f1 = (wg + 4) * 512 + lane * 8;
    const int kc0 = f0 >> 9, kt0 = (f0 >> 3) & 63;
    const int kc1 = f1 >> 9, kt1 = (f1 >> 3) & 63;
    bf16* const Kbase = smem + grp * 8192;
    bf16* const Vbase = smem + 16384 + grp * 8192;

#define STAGE(BUF, T0) do { \
        bf16* Kd = Kbase + (BUF) * 4096; \
        bf16* Vd = Vbase + (BUF) * 4096; \
        async_ld16(Kp + (size_t)((T0) + kt0) * HD_DIM + kc0 * 8, Kd + wg * 512); \
        async_ld16(Kp + (size_t)((T0) + kt1) * HD_DIM + kc1 * 8, Kd + (wg + 4) * 512); \
        async_ld16(Vp + (size_t)kt0 * S_LEN + (T0) + kc0 * 8, Vd + wg * 512); \
        async_ld16(Vp + (size_t)kt1 * S_LEN + (T0) + kc1 * 8, Vd + (wg + 4) * 512); \
    } while (0)

    STAGE(0, tbase);
    // Q B-frags from global: B[q=wg*32+l31][k=(2kb+half)*8 + j] (both groups load same rows)
    bf16x8 qf[4];
    {
        const bf16* qrow = Qg + ((size_t)bh * S_LEN + q0blk + wg * 32 + l31) * HD_DIM;
#pragma unroll
        for (int kb = 0; kb < 4; ++kb)
            qf[kb] = *(const bf16x8*)(qrow + (2 * kb + half) * 8);
    }
    __syncthreads();

    float l_i = 0.f;
    floatx16 o0 = {0}, o1 = {0};   // O^T strips: rows hd 0-31 / 32-63, col q=l31

    for (int rd = 0; rd < 16; ++rd) {
        const int cur = rd & 1;
        if (rd < 15) STAGE(cur ^ 1, tbase + (rd + 1) * 64);
        const bf16* Kt = Kbase + cur * 4096;
        const bf16* Vt = Vbase + cur * 4096;
        // QK^T: sc[strip] rows t = 32*strip + (e&3)+8*(e>>2)+4*half, col q = l31
        floatx16 sc0 = {0}, sc1 = {0};
        __builtin_amdgcn_s_setprio(1);
#pragma unroll
        for (int kb = 0; kb < 4; ++kb) {
            bf16x8 k0 = *(const bf16x8*)&Kt[(2 * kb + half) * 512 + l31 * 8];
            bf16x8 k1 = *(const bf16x8*)&Kt[(2 * kb + half) * 512 + (32 + l31) * 8];
            sc0 = mfma32(k0, qf[kb], sc0);
            sc1 = mfma32(k1, qf[kb], sc1);
        }
        __builtin_amdgcn_s_setprio(0);
        // no-max softmax: P = exp2(score); pack to bf16x2 words in-register (T12).
        float rs = 0.f;
        int w0[8], w1[8];
#pragma unroll
        for (int e = 0; e < 16; e += 2) {   // strip 0: t = 0..31
            float p0 = __builtin_amdgcn_exp2f(sc0[e]);
            float p1 = __builtin_amdgcn_exp2f(sc0[e + 1]);
            rs += p0 + p1;
            bf16x2 t2 = {(bf16)p0, (bf16)p1};
            w0[e >> 1] = __builtin_bit_cast(int, t2);
        }
#pragma unroll
        for (int e = 0; e < 16; e += 2) {   // strip 1: t = 32..63
            float p0 = __builtin_amdgcn_exp2f(sc1[e]);
            float p1 = __builtin_amdgcn_exp2f(sc1[e + 1]);
            rs += p0 + p1;
            bf16x2 t2 = {(bf16)p0, (bf16)p1};
            w1[e >> 1] = __builtin_bit_cast(int, t2);
        }
        l_i += rs;
        bf16x8 pfr[4];
        pfr[0] = mkfrag(w0[0], w0[1], w0[2], w0[3]);
        pfr[1] = mkfrag(w0[4], w0[5], w0[6], w0[7]);
        pfr[2] = mkfrag(w1[0], w1[1], w1[2], w1[3]);
        pfr[3] = mkfrag(w1[4], w1[5], w1[6], w1[7]);
        // PV: O^T[hd][q] += V^T-frag x P-frag
        __builtin_amdgcn_s_setprio(1);
#pragma unroll
        for (int kb = 0; kb < 4; ++kb) {
            bf16x8 v0 = *(const bf16x8*)&Vt[(2 * kb + half) * 512 + l31 * 8];
            bf16x8 v1 = *(const bf16x8*)&Vt[(2 * kb + half) * 512 + (32 + l31) * 8];
            o0 = mfma32(v0, pfr[kb], o0);
            o1 = mfma32(v1, pfr[kb], o1);
        }
        __builtin_amdgcn_s_setprio(0);
        __syncthreads();
    }
#undef STAGE

    // combine the two lane-halves' partial l (disjoint t-subsets, same q)
    l_i += __shfl_xor(l_i, 32);

    // linear t-group merge via LDS (loop already ended on a barrier -> smem free).
    float* slabF = (float*)smem;
    float* lA = slabF + 4 * 2112;
    if (grp == 0) {
        float* S0 = slabF + wg * 2112;
#pragma unroll
        for (int s2 = 0; s2 < 2; ++s2) {
            const floatx16 oo = s2 ? o1 : o0;
#pragma unroll
            for (int e = 0; e < 16; ++e) {
                int hd = s2 * 32 + (e & 3) + 8 * (e >> 2) + 4 * half;
                S0[l31 * 66 + hd] = oo[e];     // unnormalized partial O^T
            }
        }
        if (lane < 32) lA[wg * 32 + l31] = l_i;
    }
    __syncthreads();
    if (grp == 1) {
        float* S0 = slabF + wg * 2112;
        float lt = l_i + lA[wg * 32 + l31];
        float inv = 1.f / lt;
        int b = bh >> 4, hh = bh & 15;
        bf16* Sw = smem + 17408 + wg * 1280;   // 32 q x 40 (padded) bf16
#pragma unroll
        for (int s2 = 0; s2 < 2; ++s2) {
            const floatx16 oo = s2 ? o1 : o0;
#pragma unroll
            for (int e = 0; e < 16; ++e) {
                int hd = (e & 3) + 8 * (e >> 2) + 4 * half;
                float v = (oo[e] + S0[l31 * 66 + s2 * 32 + hd]) * inv;
                Sw[l31 * 40 + hd] = (bf16)v;
            }
#pragma unroll
            for (int p = 0; p < 2; ++p) {
                int q = p * 16 + (lane >> 2), part = lane & 3;
                bf16x8 v = *(const bf16x8*)&Sw[q * 40 + part * 8];
                int s = q0blk + wg * 32 + q;
                *(bf16x8*)&ctx[((size_t)(b * S_LEN + s)) * D_DIM + hh * 64 + s2 * 32 + part * 8] = v;
            }
        }
    }
}

extern "C" void kernel_launch(void* const* d_in, const int* in_sizes, int n_in,
                              void* d_out, int out_size, void* d_ws, size_t ws_size,
                              hipStream_t stream) {
    const float* query = (const float*)d_in[0];
    const float* key   = (const float*)d_in[1];
    const float* value = (const float*)d_in[2];
    const float* Wq = (const float*)d_in[3];
    const float* bq = (const float*)d_in[4];
    const float* Wk = (const float*)d_in[5];
    const float* bk = (const float*)d_in[6];
    const float* Wv = (const float*)d_in[7];
    const float* bv = (const float*)d_in[8];
    const float* Wo = (const float*)d_in[9];
    const float* bo = (const float*)d_in[10];
    float* out = (float*)d_out;

    bf16* ws = (bf16*)d_ws;
    const size_t WSZ = (size_t)H_CNT * D_DIM * HD_DIM;
    const size_t TSZ = (size_t)B_SZ * H_CNT * S_LEN * HD_DIM;
    bf16* WqT = ws;
    bf16* WkT = WqT + WSZ;
    bf16* WvT = WkT + WSZ;
    bf16* WoT = WvT + WSZ;
    bf16* Qb  = WoT + (size_t)D_DIM * D_DIM;  // [b,h,s,hd]
    bf16* Kb  = Qb + TSZ;
    bf16* Vtb = Kb + TSZ;                     // [b,h,hd,s] -- written directly by gemm mode 2
    bf16* ctx = Vtb + TSZ;                    // [b,s,D]

    dim3 blk(256);

    PrepArgs pa;
    pa.w_src[0] = Wq; pa.w_src[1] = Wk; pa.w_src[2] = Wv;
    pa.w_dst[0] = WqT; pa.w_dst[1] = WkT; pa.w_dst[2] = WvT;
    pa.wo = Wo; pa.wo_t = WoT;
    prep<<<dim3(4096), blk, 0, stream>>>(pa);

    GemmArgs qkv;
    qkv.p[0] = {query, WqT, bq, Qb, QSCALE, 1};
    qkv.p[1] = {key,   WkT, bk, Kb, 1.0f, 1};
    qkv.p[2] = {value, WvT, bv, Vtb, 1.0f, 2};   // V writes V^T directly
    gemm_bt<<<dim3(32, 8, 3), blk, 0, stream>>>(qkv);

    attn<<<dim3(512), dim3(512), 0, stream>>>(Qb, Kb, Vtb, ctx);

    gemm_out64<<<dim3(64, 16), blk, 0, stream>>>(ctx, WoT, bo, out);
}

// Round 9
// 217.142 us; speedup vs baseline: 1.0421x; 1.0421x over previous
//
#include <hip/hip_runtime.h>
#include <hip/hip_bf16.h>

typedef __bf16 bf16;
typedef __bf16 bf16x8 __attribute__((ext_vector_type(8)));
typedef __bf16 bf16x4 __attribute__((ext_vector_type(4)));
typedef __bf16 bf16x2 __attribute__((ext_vector_type(2)));
typedef float floatx4 __attribute__((ext_vector_type(4)));
typedef float floatx16 __attribute__((ext_vector_type(16)));
typedef int intx4 __attribute__((ext_vector_type(4)));

#define B_SZ 2
#define S_LEN 2048
#define D_DIM 1024
#define H_CNT 16
#define HD_DIM 64
#define M_ROWS 4096   // B*S
#define QSCALE 0.18033688011112042f  // 0.125 * log2(e): scores come out in base-2 domain

__device__ __forceinline__ void async_ld16(const void* g, void* s) {
    __builtin_amdgcn_global_load_lds((const __attribute__((address_space(1))) void*)g,
                                     (__attribute__((address_space(3))) void*)s, 16, 0, 0);
}

__device__ __forceinline__ floatx4 mfma16(bf16x8 a, bf16x8 b, floatx4 c) {
    return __builtin_amdgcn_mfma_f32_16x16x32_bf16(a, b, c, 0, 0, 0);
}
__device__ __forceinline__ floatx16 mfma32(bf16x8 a, bf16x8 b, floatx16 c) {
    return __builtin_amdgcn_mfma_f32_32x32x16_bf16(a, b, c, 0, 0, 0);
}

// T12 fragment assembly: one permlane32_swap fills two output words (validated R1/R4).
__device__ __forceinline__ bf16x8 mkfrag(int a0, int a1, int b0, int b1) {
    asm("v_permlane32_swap_b32 %0, %1" : "+v"(a0), "+v"(b0));
    asm("v_permlane32_swap_b32 %0, %1" : "+v"(a1), "+v"(b1));
    intx4 q = {a0, a1, b0, b1};
    return __builtin_bit_cast(bf16x8, q);
}

// ---------------- merged prep: input casts + all weight transposes, one launch ----------------
// (Kept permanently: both attempts to fold the input cast into the GEMM lost 25-30us
//  -- R5 reg-staging serialized HBM latency into each K-step; R8 f32-LDS staging hit
//  3.1M bank conflicts + 2x A-tile LDS traffic. The 72MB round-trip is the cheap option.)
struct PrepArgs {
    const float* cast_src[3]; bf16* cast_dst[3];
    const float* w_src[3];    bf16* w_dst[3];
    const float* wo;          bf16* wo_t;
};
__global__ __launch_bounds__(256) void prep(PrepArgs a) {
    __shared__ bf16 tile[32][33];
    const int bx = blockIdx.x, tid = threadIdx.x;
    if (bx < 12288) {
        const int t = bx >> 12, blk = bx & 4095;
        const float* s = a.cast_src[t];
        bf16* d = a.cast_dst[t];
        size_t i = ((size_t)blk * 256 + tid) * 4;
        float4 v = *(const float4*)(s + i);
        bf16x4 o = { (bf16)v.x, (bf16)v.y, (bf16)v.z, (bf16)v.w };
        *(bf16x4*)(d + i) = o;
        return;
    }
    int tx = tid & 31, ty = tid >> 5;
    const float* src; bf16* dst; int r0, c0, C, R;
    if (bx < 15360) {
        int idx = bx - 12288;
        int z = idx >> 6, xy = idx & 63;
        int mat = z >> 4, head = z & 15;
        src = a.w_src[mat] + (size_t)head * D_DIM * HD_DIM;  // [1024][64]
        dst = a.w_dst[mat] + (size_t)head * D_DIM * HD_DIM;  // [64][1024]
        r0 = (xy & 31) * 32; c0 = (xy >> 5) * 32; C = HD_DIM; R = D_DIM;
    } else {
        int idx = bx - 15360;
        src = a.wo; dst = a.wo_t;
        r0 = (idx & 31) * 32; c0 = (idx >> 5) * 32; C = D_DIM; R = D_DIM;
    }
#pragma unroll
    for (int i = 0; i < 32; i += 8)
        tile[ty + i][tx] = (bf16)src[(size_t)(r0 + ty + i) * C + c0 + tx];
    __syncthreads();
#pragma unroll
    for (int i = 0; i < 32; i += 8)
        dst[(size_t)(c0 + ty + i) * R + r0 + tx] = tile[tx][ty + i];
}

// ---------------- QKV GEMM: 128x128 tile, 512 threads / 8 waves of 64x32 ----------------
// R9 change: same K-loop, barriers, staging swizzle and LDS image as the validated
// 256-thread version -- only issue->wave mapping (8 issues over 8 waves) and the
// wave->output decomposition (8 waves of 64x32, acc[4][2]) changed. 768 blocks of
// 8 waves = 24 waves/CU = 6 waves/SIMD (was 3): the same TLP mechanism that won
// R4 (attn) and R7 (og). mode: 1 = bf16 [b,h,s,hd]; 2 = bf16 V^T [b,h,hd,s]
struct GemmPtrs { const bf16* A; const bf16* BT; const float* bias; bf16* C;
                  float scale; int mode; };
struct GemmArgs { GemmPtrs p[3]; };

__global__ __launch_bounds__(512, 4) void gemm_bt(GemmArgs args) {
    __shared__ __align__(16) bf16 As[128 * 32];
    __shared__ __align__(16) bf16 Bs[128 * 32];
    const GemmPtrs P = args.p[blockIdx.z];
    const int tid = threadIdx.x, wave = tid >> 6, lane = tid & 63;
    const int quad = lane >> 4, l15 = lane & 15;
    const int bm = blockIdx.x * 128, bn = blockIdx.y * 128;
    const int wm = (wave >> 2) * 64, wn = (wave & 3) * 32;   // 2x4 waves, 64x32 each

    floatx4 acc[4][2];
#pragma unroll
    for (int i = 0; i < 4; i++)
#pragma unroll
        for (int j = 0; j < 2; j++) acc[i][j] = (floatx4){0.f, 0.f, 0.f, 0.f};

    const int srow = (lane >> 2);
    const int scol = (((lane & 3) ^ ((srow >> 1) & 3)) << 3);  // swizzled source chunk
    const int ck = ((quad ^ ((l15 >> 1) & 3)) << 3);           // swizzled read chunk
    for (int k0 = 0; k0 < 1024; k0 += 32) {
        {   // one A-issue + one B-issue per wave (issue == wave, rows wave*16..+15)
            int row = wave * 16 + srow;
            async_ld16(P.A + (size_t)(bm + row) * 1024 + k0 + scol, &As[wave * 512]);
            async_ld16(P.BT + (size_t)(bn + row) * 1024 + k0 + scol, &Bs[wave * 512]);
        }
        __syncthreads();
        bf16x8 af[4], bfr[2];
#pragma unroll
        for (int mi = 0; mi < 4; mi++)
            af[mi] = *(const bf16x8*)&As[(wm + mi * 16 + l15) * 32 + ck];
#pragma unroll
        for (int ni = 0; ni < 2; ni++)
            bfr[ni] = *(const bf16x8*)&Bs[(wn + ni * 16 + l15) * 32 + ck];
#pragma unroll
        for (int mi = 0; mi < 4; mi++)
#pragma unroll
            for (int ni = 0; ni < 2; ni++) acc[mi][ni] = mfma16(af[mi], bfr[ni], acc[mi][ni]);
        __syncthreads();
    }
#pragma unroll
    for (int ni = 0; ni < 2; ni++) {
        int col = bn + wn + ni * 16 + l15;
        float bb = P.bias[col];
#pragma unroll
        for (int mi = 0; mi < 4; mi++) {
#pragma unroll
            for (int r = 0; r < 4; r++) {
                int row = bm + wm + mi * 16 + quad * 4 + r;
                float v = (acc[mi][ni][r] + bb) * P.scale;
                int b = row >> 11, s2 = row & 2047, h = col >> 6, hd = col & 63;
                if (P.mode == 1)
                    P.C[(((size_t)(b * H_CNT + h)) * S_LEN + s2) * HD_DIM + hd] = (bf16)v;
                else  // mode 2: V^T [b,h,hd,s]
                    P.C[(((size_t)(b * H_CNT + h)) * HD_DIM + hd) * S_LEN + s2] = (bf16)v;
            }
        }
    }
}

// ---------------- output GEMM: 64x64 tiles, 4 blocks/CU (R7, banked -3.4us) ----------------
__global__ __launch_bounds__(256) void gemm_out64(const bf16* __restrict__ A,
                                                  const bf16* __restrict__ BT,
                                                  const float* __restrict__ bias,
                                                  float* __restrict__ Cf) {
    __shared__ __align__(16) bf16 As[64 * 32];
    __shared__ __align__(16) bf16 Bs[64 * 32];
    const int tid = threadIdx.x, wave = tid >> 6, lane = tid & 63;
    const int quad = lane >> 4, l15 = lane & 15;
    const int bm = blockIdx.x * 64, bn = blockIdx.y * 64;
    const int wm = (wave >> 1) * 32, wn = (wave & 1) * 32;

    floatx4 acc[2][2];
#pragma unroll
    for (int i = 0; i < 2; i++)
#pragma unroll
        for (int j = 0; j < 2; j++) acc[i][j] = (floatx4){0.f, 0.f, 0.f, 0.f};

    const int srow = (lane >> 2);
    const int scol = (((lane & 3) ^ ((srow >> 1) & 3)) << 3);
    const int ck = ((quad ^ ((l15 >> 1) & 3)) << 3);
    for (int k0 = 0; k0 < 1024; k0 += 32) {
        {
            int row = wave * 16 + srow;
            async_ld16(A  + (size_t)(bm + row) * 1024 + k0 + scol, &As[wave * 512]);
            async_ld16(BT + (size_t)(bn + row) * 1024 + k0 + scol, &Bs[wave * 512]);
        }
        __syncthreads();
        bf16x8 af[2], bfr[2];
#pragma unroll
        for (int mi = 0; mi < 2; mi++)
            af[mi] = *(const bf16x8*)&As[(wm + mi * 16 + l15) * 32 + ck];
#pragma unroll
        for (int ni = 0; ni < 2; ni++)
            bfr[ni] = *(const bf16x8*)&Bs[(wn + ni * 16 + l15) * 32 + ck];
#pragma unroll
        for (int mi = 0; mi < 2; mi++)
#pragma unroll
            for (int ni = 0; ni < 2; ni++) acc[mi][ni] = mfma16(af[mi], bfr[ni], acc[mi][ni]);
        __syncthreads();
    }
#pragma unroll
    for (int ni = 0; ni < 2; ni++) {
        int col = bn + wn + ni * 16 + l15;
        float bb = bias[col];
#pragma unroll
        for (int mi = 0; mi < 2; mi++) {
#pragma unroll
            for (int r = 0; r < 4; r++) {
                int row = bm + wm + mi * 16 + quad * 4 + r;
                Cf[(size_t)row * 1024 + col] = acc[mi][ni][r] + bb;
            }
        }
    }
}

// ---------------- flash attention: t-split 2-way inside a 512-thread block ----------------
// R4 body verbatim (best measured: 47.6-48.6us, occupancy 33%, VGPR 56, MfmaUtil ~28%).
// R6 taught: 8 waves/SIMD impossible (o+qf+sc state > 64 VGPR -> forced spill).
__global__ __launch_bounds__(512, 4) void attn(const bf16* __restrict__ Qg, const bf16* __restrict__ Kg,
                                               const bf16* __restrict__ Vtg, bf16* __restrict__ ctx) {
    __shared__ __align__(16) bf16 smem[32768];    // 64 KB
    const int tid = threadIdx.x, wave = tid >> 6, lane = tid & 63;
    const int l31 = lane & 31, half = lane >> 5;
    const int grp = wave >> 2, wg = wave & 3;     // t-group, wave-in-group
    const int bid = blockIdx.x;
    const int bh = (bid >> 1) & 31;               // L2 swizzle bijection
    const int qb = ((bid >> 6) << 1) | (bid & 1);
    const int q0blk = qb * 128;
    const bf16* Kp = Kg + (size_t)bh * S_LEN * HD_DIM;
    const bf16* Vp = Vtg + (size_t)bh * HD_DIM * S_LEN;
    const int tbase = grp * 1024;

    const int f0 = wg * 512 + lane * 8, f1 = (wg + 4) * 512 + lane * 8;
    const int kc0 = f0 >> 9, kt0 = (f0 >> 3) & 63;
    const int kc1 = f1 >> 9, kt1 = (f1 >> 3) & 63;
    bf16* const Kbase = smem + grp * 8192;
    bf16* const Vbase = smem + 16384 + grp * 8192;

#define STAGE(BUF, T0) do { \
        bf16* Kd = Kbase + (BUF) * 4096; \
        bf16* Vd = Vbase + (BUF) * 4096; \
        async_ld16(Kp + (size_t)((T0) + kt0) * HD_DIM + kc0 * 8, Kd + wg * 512); \
        async_ld16(Kp + (size_t)((T0) + kt1) * HD_DIM + kc1 * 8, Kd + (wg + 4) * 512); \
        async_ld16(Vp + (size_t)kt0 * S_LEN + (T0) + kc0 * 8, Vd + wg * 512); \
        async_ld16(Vp + (size_t)kt1 * S_LEN + (T0) + kc1 * 8, Vd + (wg + 4) * 512); \
    } while (0)

    STAGE(0, tbase);
    // Q B-frags from global: B[q=wg*32+l31][k=(2kb+half)*8 + j] (both groups load same rows)
    bf16x8 qf[4];
    {
        const bf16* qrow = Qg + ((size_t)bh * S_LEN + q0blk + wg * 32 + l31) * HD_DIM;
#pragma unroll
        for (int kb = 0; kb < 4; ++kb)
            qf[kb] = *(const bf16x8*)(qrow + (2 * kb + half) * 8);
    }
    __syncthreads();

    float l_i = 0.f;
    floatx16 o0 = {0}, o1 = {0};   // O^T strips: rows hd 0-31 / 32-63, col q=l31

    for (int rd = 0; rd < 16; ++rd) {
        const int cur = rd & 1;
        if (rd < 15) STAGE(cur ^ 1, tbase + (rd + 1) * 64);
        const bf16* Kt = Kbase + cur * 4096;
        const bf16* Vt = Vbase + cur * 4096;
        // QK^T: sc[strip] rows t = 32*strip + (e&3)+8*(e>>2)+4*half, col q = l31
        floatx16 sc0 = {0}, sc1 = {0};
        __builtin_amdgcn_s_setprio(1);
#pragma unroll
        for (int kb = 0; kb < 4; ++kb) {
            bf16x8 k0 = *(const bf16x8*)&Kt[(2 * kb + half) * 512 + l31 * 8];
            bf16x8 k1 = *(const bf16x8*)&Kt[(2 * kb + half) * 512 + (32 + l31) * 8];
            sc0 = mfma32(k0, qf[kb], sc0);
            sc1 = mfma32(k1, qf[kb], sc1);
        }
        __builtin_amdgcn_s_setprio(0);
        // no-max softmax: P = exp2(score); pack to bf16x2 words in-register (T12).
        float rs = 0.f;
        int w0[8], w1[8];
#pragma unroll
        for (int e = 0; e < 16; e += 2) {   // strip 0: t = 0..31
            float p0 = __builtin_amdgcn_exp2f(sc0[e]);
            float p1 = __builtin_amdgcn_exp2f(sc0[e + 1]);
            rs += p0 + p1;
            bf16x2 t2 = {(bf16)p0, (bf16)p1};
            w0[e >> 1] = __builtin_bit_cast(int, t2);
        }
#pragma unroll
        for (int e = 0; e < 16; e += 2) {   // strip 1: t = 32..63
            float p0 = __builtin_amdgcn_exp2f(sc1[e]);
            float p1 = __builtin_amdgcn_exp2f(sc1[e + 1]);
            rs += p0 + p1;
            bf16x2 t2 = {(bf16)p0, (bf16)p1};
            w1[e >> 1] = __builtin_bit_cast(int, t2);
        }
        l_i += rs;
        bf16x8 pfr[4];
        pfr[0] = mkfrag(w0[0], w0[1], w0[2], w0[3]);
        pfr[1] = mkfrag(w0[4], w0[5], w0[6], w0[7]);
        pfr[2] = mkfrag(w1[0], w1[1], w1[2], w1[3]);
        pfr[3] = mkfrag(w1[4], w1[5], w1[6], w1[7]);
        // PV: O^T[hd][q] += V^T-frag x P-frag
        __builtin_amdgcn_s_setprio(1);
#pragma unroll
        for (int kb = 0; kb < 4; ++kb) {
            bf16x8 v0 = *(const bf16x8*)&Vt[(2 * kb + half) * 512 + l31 * 8];
            bf16x8 v1 = *(const bf16x8*)&Vt[(2 * kb + half) * 512 + (32 + l31) * 8];
            o0 = mfma32(v0, pfr[kb], o0);
            o1 = mfma32(v1, pfr[kb], o1);
        }
        __builtin_amdgcn_s_setprio(0);
        __syncthreads();
    }
#undef STAGE

    // combine the two lane-halves' partial l (disjoint t-subsets, same q)
    l_i += __shfl_xor(l_i, 32);

    // linear t-group merge via LDS (loop already ended on a barrier -> smem free).
    float* slabF = (float*)smem;
    float* lA = slabF + 4 * 2112;
    if (grp == 0) {
        float* S0 = slabF + wg * 2112;
#pragma unroll
        for (int s2 = 0; s2 < 2; ++s2) {
            const floatx16 oo = s2 ? o1 : o0;
#pragma unroll
            for (int e = 0; e < 16; ++e) {
                int hd = s2 * 32 + (e & 3) + 8 * (e >> 2) + 4 * half;
                S0[l31 * 66 + hd] = oo[e];     // unnormalized partial O^T
            }
        }
        if (lane < 32) lA[wg * 32 + l31] = l_i;
    }
    __syncthreads();
    if (grp == 1) {
        float* S0 = slabF + wg * 2112;
        float lt = l_i + lA[wg * 32 + l31];
        float inv = 1.f / lt;
        int b = bh >> 4, hh = bh & 15;
        bf16* Sw = smem + 17408 + wg * 1280;   // 32 q x 40 (padded) bf16
#pragma unroll
        for (int s2 = 0; s2 < 2; ++s2) {
            const floatx16 oo = s2 ? o1 : o0;
#pragma unroll
            for (int e = 0; e < 16; ++e) {
                int hd = (e & 3) + 8 * (e >> 2) + 4 * half;
                float v = (oo[e] + S0[l31 * 66 + s2 * 32 + hd]) * inv;
                Sw[l31 * 40 + hd] = (bf16)v;
            }
#pragma unroll
            for (int p = 0; p < 2; ++p) {
                int q = p * 16 + (lane >> 2), part = lane & 3;
                bf16x8 v = *(const bf16x8*)&Sw[q * 40 + part * 8];
                int s = q0blk + wg * 32 + q;
                *(bf16x8*)&ctx[((size_t)(b * S_LEN + s)) * D_DIM + hh * 64 + s2 * 32 + part * 8] = v;
            }
        }
    }
}

extern "C" void kernel_launch(void* const* d_in, const int* in_sizes, int n_in,
                              void* d_out, int out_size, void* d_ws, size_t ws_size,
                              hipStream_t stream) {
    const float* query = (const float*)d_in[0];
    const float* key   = (const float*)d_in[1];
    const float* value = (const float*)d_in[2];
    const float* Wq = (const float*)d_in[3];
    const float* bq = (const float*)d_in[4];
    const float* Wk = (const float*)d_in[5];
    const float* bk = (const float*)d_in[6];
    const float* Wv = (const float*)d_in[7];
    const float* bv = (const float*)d_in[8];
    const float* Wo = (const float*)d_in[9];
    const float* bo = (const float*)d_in[10];
    float* out = (float*)d_out;

    bf16* ws = (bf16*)d_ws;
    const size_t ASZ = (size_t)M_ROWS * D_DIM;
    const size_t WSZ = (size_t)H_CNT * D_DIM * HD_DIM;
    const size_t TSZ = (size_t)B_SZ * H_CNT * S_LEN * HD_DIM;
    bf16* Qc  = ws;
    bf16* Kc  = Qc + ASZ;
    bf16* Vc  = Kc + ASZ;
    bf16* WqT = Vc + ASZ;
    bf16* WkT = WqT + WSZ;
    bf16* WvT = WkT + WSZ;
    bf16* WoT = WvT + WSZ;
    bf16* Qb  = WoT + (size_t)D_DIM * D_DIM;  // [b,h,s,hd]
    bf16* Kb  = Qb + TSZ;
    bf16* Vtb = Kb + TSZ;                     // [b,h,hd,s] -- written directly by gemm mode 2
    bf16* ctx = Vtb + TSZ;                    // [b,s,D]

    dim3 blk(256);

    PrepArgs pa;
    pa.cast_src[0] = query; pa.cast_src[1] = key; pa.cast_src[2] = value;
    pa.cast_dst[0] = Qc;    pa.cast_dst[1] = Kc;  pa.cast_dst[2] = Vc;
    pa.w_src[0] = Wq; pa.w_src[1] = Wk; pa.w_src[2] = Wv;
    pa.w_dst[0] = WqT; pa.w_dst[1] = WkT; pa.w_dst[2] = WvT;
    pa.wo = Wo; pa.wo_t = WoT;
    prep<<<dim3(16384), blk, 0, stream>>>(pa);

    GemmArgs qkv;
    qkv.p[0] = {Qc, WqT, bq, Qb, QSCALE, 1};
    qkv.p[1] = {Kc, WkT, bk, Kb, 1.0f, 1};
    qkv.p[2] = {Vc, WvT, bv, Vtb, 1.0f, 2};   // V writes V^T directly
    gemm_bt<<<dim3(32, 8, 3), dim3(512), 0, stream>>>(qkv);

    attn<<<dim3(512), dim3(512), 0, stream>>>(Qb, Kb, Vtb, ctx);

    gemm_out64<<<dim3(64, 16), blk, 0, stream>>>(ctx, WoT, bo, out);
}